// Round 4
// baseline (345.376 us; speedup 1.0000x reference)
//
#include <hip/hip_runtime.h>

// Quantize/dequantize with 64-level sorted codebook (L=64).
//   r = x - means
//   pos = clip(searchsorted(cb, r), 1, 63)           // side='left'
//   sym = (r - cb[pos-1] <= cb[pos] - r) ? pos-1 : pos
//   y_hat = cb[sym] + means
// FP ops replicate the JAX reference exactly -> absmax 0.
//
// R4 design (R3 was latency-bound: 9-deep dependent LDS chain, VGPR=20):
//  - search steps s=32,16,8,4 use a register tree of 15 wave-uniform codebook
//    values (scalar-loaded once) selected by v_cndmask: ~4cyc/hop, not ~120.
//  - steps s=2,1 and the (left,right) fetch use __shfl (ds_bpermute): lane i
//    holds cb[i] (L=64 == wave size) -> conflict-free crossbar, no LDS array,
//    no __syncthreads.
//  - __launch_bounds__(256,4): 128-VGPR budget so all 4 global loads + 8
//    independent search chains stay in flight (R3's 20-VGPR serialization).

typedef float v4f __attribute__((ext_vector_type(4)));

struct Tree {
    float c31;
    float c15, c47;
    float c07, c23, c39, c55;
    float c03, c11, c19, c27, c35, c43, c51, c59;
};

__device__ __forceinline__ void nearest(const Tree& t, float cbreg,
                                        float r, float m,
                                        float& sym, float& y)
{
    // lower_bound p = #{ j : cb[j] < r }, descended as a binary tree.
    int p = (t.c31 < r) ? 32 : 0;                       // s=32, cb[31]

    float v = (p & 32) ? t.c47 : t.c15;                 // s=16, cb[p+15]
    p += (v < r) ? 16 : 0;

    float u0 = (p & 16) ? t.c23 : t.c07;                // s=8, cb[p+7]
    float u1 = (p & 16) ? t.c55 : t.c39;
    v = (p & 32) ? u1 : u0;
    p += (v < r) ? 8 : 0;

    float w0 = (p & 8) ? t.c11 : t.c03;                 // s=4, cb[p+3]
    float w1 = (p & 8) ? t.c27 : t.c19;
    float w2 = (p & 8) ? t.c43 : t.c35;
    float w3 = (p & 8) ? t.c59 : t.c51;
    float w4 = (p & 16) ? w1 : w0;
    float w5 = (p & 16) ? w3 : w2;
    v = (p & 32) ? w5 : w4;
    p += (v < r) ? 4 : 0;

    v = __shfl(cbreg, p + 1);                           // s=2, cb[p+1]
    p += (v < r) ? 2 : 0;
    v = __shfl(cbreg, p);                               // s=1, cb[p]
    p += (v < r) ? 1 : 0;

    p = min(max(p, 1), 63);
    const float left  = __shfl(cbreg, p - 1);           // independent pair
    const float right = __shfl(cbreg, p);
    const bool tie = (r - left) <= (right - r);
    sym = (float)(tie ? p - 1 : p);
    y   = (tie ? left : right) + m;
}

__global__ __launch_bounds__(256, 4) void quant_dequant_kernel(
    const v4f* __restrict__ x4,
    const v4f* __restrict__ m4,
    const float* __restrict__ codebook,
    v4f* __restrict__ sym_out,   // symbols as float values
    v4f* __restrict__ yhat_out,
    int n8)                      // n/8
{
    // lane i holds cb[i]; L=64 == wavefront size
    const float cbreg = codebook[threadIdx.x & 63];

    Tree t;
    t.c31 = codebook[31];
    t.c15 = codebook[15]; t.c47 = codebook[47];
    t.c07 = codebook[7];  t.c23 = codebook[23];
    t.c39 = codebook[39]; t.c55 = codebook[55];
    t.c03 = codebook[3];  t.c11 = codebook[11];
    t.c19 = codebook[19]; t.c27 = codebook[27];
    t.c35 = codebook[35]; t.c43 = codebook[43];
    t.c51 = codebook[51]; t.c59 = codebook[59];

    const int i = blockIdx.x * blockDim.x + threadIdx.x;
    if (i >= n8) return;
    const int j = i + n8;

    // all global loads up front
    const v4f xa = x4[i];
    const v4f ma = m4[i];
    const v4f xb = x4[j];
    const v4f mb = m4[j];

    v4f sa, ya, sb, yb;
#pragma unroll
    for (int k = 0; k < 4; ++k) {
        float s0, y0, s1, y1;
        nearest(t, cbreg, xa[k] - ma[k], ma[k], s0, y0);
        nearest(t, cbreg, xb[k] - mb[k], mb[k], s1, y1);
        sa[k] = s0; ya[k] = y0;
        sb[k] = s1; yb[k] = y1;
    }

    __builtin_nontemporal_store(sa, &sym_out[i]);
    __builtin_nontemporal_store(ya, &yhat_out[i]);
    __builtin_nontemporal_store(sb, &sym_out[j]);
    __builtin_nontemporal_store(yb, &yhat_out[j]);
}

extern "C" void kernel_launch(void* const* d_in, const int* in_sizes, int n_in,
                              void* d_out, int out_size, void* d_ws, size_t ws_size,
                              hipStream_t stream)
{
    const float* x     = (const float*)d_in[0];
    const float* means = (const float*)d_in[1];
    const float* cb    = (const float*)d_in[2];

    const int n  = in_sizes[0];      // 25,165,824
    const int n8 = n / 8;            // 3,145,728

    float* out = (float*)d_out;      // [0..n): symbols (as float), [n..2n): y_hat

    const int block = 256;
    const int grid  = (n8 + block - 1) / block;   // 12288

    quant_dequant_kernel<<<grid, block, 0, stream>>>(
        (const v4f*)x, (const v4f*)means, cb,
        (v4f*)out, (v4f*)(out + n), n8);
}